// Round 3
// baseline (550.077 us; speedup 1.0000x reference)
//
#include <hip/hip_runtime.h>
#include <hip/hip_bf16.h>

typedef short short8 __attribute__((ext_vector_type(8)));
typedef float floatx4 __attribute__((ext_vector_type(4)));

#define NGROUP 512
#define RREG 256
#define D 512
#define FBAR_ELEMS (NGROUP * D)   // 262144

__device__ __forceinline__ unsigned short f2bf(float f) {
    unsigned int u = __float_as_uint(f);
    unsigned int r = (u + 0x7fffu + ((u >> 16) & 1u)) >> 16;
    return (unsigned short)r;
}
__device__ __forceinline__ float bf2f(unsigned short h) {
    return __uint_as_float(((unsigned int)h) << 16);
}
__device__ __forceinline__ float fast_tanh(float x) {
    // tanh(x) = (e^{2x}-1)/(e^{2x}+1); clamp so exp can't overflow.
    float cx = fminf(fmaxf(x, -9.5f), 9.5f);
    float e  = __builtin_amdgcn_exp2f(cx * 2.8853900817779268f);  // e^{2cx}
    return (e - 1.f) * __builtin_amdgcn_rcpf(e + 1.f);
}

// ---- kernel 1: W1 fp32 -> bf16, PRE-SWIZZLED chunk layout ----
// Chunk nc (64 cols x 512 k): desired LDS image byte L holds
// W1bf[col = nc*64 + L/1024][k elem ((L%1024) ^ ((col&7)<<4))/2].
// Stored linearly so global_load_lds (linear dest) reproduces the swizzled image.
__global__ __launch_bounds__(256) void conv_w1(const float* __restrict__ W1,
                                               unsigned short* __restrict__ W1s) {
    int tid = blockIdx.x * 256 + threadIdx.x;   // 0..65535
    int G = tid * 8;                            // byte offset in 512 KiB
    int nc = G >> 16;
    int L = G & 65535;
    int col_local = L >> 10;
    int sw = L & 1023;
    int k16 = (sw ^ ((col_local & 7) << 4)) >> 4;
    int j0 = (sw & 15) >> 1;                    // 0 or 4
    int col = nc * 64 + col_local;
    const float* src = W1 + col * 512 + k16 * 8 + j0;
    float4 v = *reinterpret_cast<const float4*>(src);
    ushort4 o;
    o.x = f2bf(v.x); o.y = f2bf(v.y); o.z = f2bf(v.z); o.w = f2bf(v.w);
    *reinterpret_cast<ushort4*>((char*)W1s + G) = o;
}

// ---- kernel 2: fully fused per-group kernel ----
// 512 blocks x 1024 threads (16 waves, 16 rows/wave). bf16(x) A-frags in
// registers (64 VGPR); inv-norm folded into epilogue + pooling weights;
// W1 double-buffered through LDS via global_load_lds.
__global__ __launch_bounds__(1024, 4) void fused(
    const float* __restrict__ x, const unsigned short* __restrict__ W1s,
    const float* __restrict__ b1, const float* __restrict__ W2v,
    float* __restrict__ out) {

    __shared__ unsigned short B_lds[2][32768];   // 2 x 64 KiB (swizzled W1 chunk)
    __shared__ float scores_s[RREG];
    __shared__ float alpha_s[RREG];

    const int t = threadIdx.x;
    const int lane = t & 63;
    const int w = t >> 6;          // wave 0..15
    const int cl = lane & 15;
    const int hi = lane >> 4;
    const int bid = blockIdx.x;
    const size_t row0 = (size_t)bid * RREG;

    // stage one 64-col W1 chunk into LDS buffer `buf` (linear dest; source pre-swizzled)
    auto stage = [&](int buf, int nc) {
        const char* gb = (const char*)W1s + nc * 65536 + w * 4096 + lane * 16;
        char* lb = (char*)B_lds[buf] + w * 4096;
        #pragma unroll
        for (int i = 0; i < 4; ++i) {
            __builtin_amdgcn_global_load_lds(
                (const __attribute__((address_space(1))) void*)(gb + i * 1024),
                (__attribute__((address_space(3))) void*)(lb + i * 1024),
                16, 0, 0);
        }
    };

    stage(0, 0);   // in flight during the x-load phase

    // ---- load x, pack bf16 A-frags immediately, accumulate sum-of-squares ----
    // Lane (cl,hi): row = w*16+cl; a[c] holds k = c*32 + hi*8 + j.
    short8 a[16];
    float ss = 0.f;
    {
        const float* xp = x + (row0 + w * 16 + cl) * D + hi * 8;
        #pragma unroll
        for (int c = 0; c < 16; ++c) {
            float4 p = *reinterpret_cast<const float4*>(xp + c * 32);
            float4 q = *reinterpret_cast<const float4*>(xp + c * 32 + 4);
            ss += p.x*p.x + p.y*p.y + p.z*p.z + p.w*p.w;
            ss += q.x*q.x + q.y*q.y + q.z*q.z + q.w*q.w;
            short8 s;
            s[0] = (short)f2bf(p.x); s[1] = (short)f2bf(p.y);
            s[2] = (short)f2bf(p.z); s[3] = (short)f2bf(p.w);
            s[4] = (short)f2bf(q.x); s[5] = (short)f2bf(q.y);
            s[6] = (short)f2bf(q.z); s[7] = (short)f2bf(q.w);
            a[c] = s;
        }
    }
    // row total: lanes {cl, cl+16, cl+32, cl+48} hold partials of row w*16+cl
    ss += __shfl_xor(ss, 16, 64);
    ss += __shfl_xor(ss, 32, 64);
    const float inv = 1.0f / fmaxf(sqrtf(ss), 1e-12f);   // inv_norm of row w*16+cl

    // accumulator row r = hi*4+i needs inv of row r: broadcast from lane cl=r
    float ivr[4];
    #pragma unroll
    for (int i = 0; i < 4; ++i) ivr[i] = __shfl(inv, hi * 4 + i, 16);

    __syncthreads();   // stage(0) landed (barrier drains vmcnt)

    // ---- GEMM over 8 column-chunks; epilogue folds inv, tanh, w2-dot ----
    float sp[4] = {0.f, 0.f, 0.f, 0.f};

    for (int nc = 0; nc < 8; ++nc) {
        if (nc < 7) stage((nc + 1) & 1, nc + 1);   // prefetch next chunk

        const char* B = (const char*)B_lds[nc & 1];
        floatx4 acc[4];
        #pragma unroll
        for (int j = 0; j < 4; ++j) acc[j] = floatx4{0, 0, 0, 0};

        #pragma unroll
        for (int kk = 0; kk < 16; ++kk) {
            const int kb = kk * 64 + hi * 16;
            #pragma unroll
            for (int j = 0; j < 4; ++j) {
                const int bcol = j * 16 + cl;
                short8 bf = *reinterpret_cast<const short8*>(
                    B + bcol * 1024 + (kb ^ ((bcol & 7) << 4)));
                acc[j] = __builtin_amdgcn_mfma_f32_16x16x32_bf16(a[kk], bf, acc[j], 0, 0, 0);
            }
        }

        #pragma unroll
        for (int j = 0; j < 4; ++j) {
            int col = nc * 64 + j * 16 + cl;
            float wv = W2v[col];
            float bb = b1[col];
            #pragma unroll
            for (int i = 0; i < 4; ++i)
                sp[i] += wv * fast_tanh(acc[j][i] * ivr[i] + bb);
        }
        __syncthreads();   // all waves done with buf[nc&1]; prefetch drained
    }

    // ---- reduce score partials over the 16 column-lanes; C/D row = hi*4+i ----
    #pragma unroll
    for (int i = 0; i < 4; ++i) {
        float vv = sp[i];
        vv += __shfl_xor(vv, 1, 64);
        vv += __shfl_xor(vv, 2, 64);
        vv += __shfl_xor(vv, 4, 64);
        vv += __shfl_xor(vv, 8, 64);
        if (cl == 0) scores_s[w * 16 + hi * 4 + i] = vv;
    }
    __syncthreads();

    // ---- block softmax over 256 region scores (B_lds reused as scratch) ----
    float* F = (float*)B_lds;
    float e = 0.f, scv = 0.f;
    if (t < RREG) { scv = scores_s[t]; F[t] = scv; }
    __syncthreads();
    for (int off = 128; off > 0; off >>= 1) {
        if (t < off) F[t] = fmaxf(F[t], F[t + off]);
        __syncthreads();
    }
    float mx = F[0];
    __syncthreads();
    if (t < RREG) { e = expf(scv - mx); F[t] = e; }
    __syncthreads();
    for (int off = 128; off > 0; off >>= 1) {
        if (t < off) F[t] += F[t + off];
        __syncthreads();
    }
    float denom = F[0];
    __syncthreads();
    if (t < RREG) {
        float al = e / denom;
        alpha_s[t] = al;
        out[FBAR_ELEMS + (size_t)bid * RREG + t] = al;   // output 1: alphas
    }
    __syncthreads();

    // ---- pooling: fbar[d] = sum_r (alpha_r * inv_r) * x[r][d] from A-frags ----
    float* wred = (float*)B_lds;    // [16 waves][512 d] = 32 KiB
    {
        float wt = alpha_s[w * 16 + cl] * inv;
        #pragma unroll
        for (int c = 0; c < 16; ++c) {
            #pragma unroll
            for (int j = 0; j < 8; ++j) {
                float vv = wt * bf2f((unsigned short)a[c][j]);
                vv += __shfl_xor(vv, 1, 64);
                vv += __shfl_xor(vv, 2, 64);
                vv += __shfl_xor(vv, 4, 64);
                vv += __shfl_xor(vv, 8, 64);
                if (cl == 0) wred[w * 512 + c * 32 + hi * 8 + j] = vv;
            }
        }
    }
    __syncthreads();
    if (t < D) {
        float s = 0.f;
        #pragma unroll
        for (int q = 0; q < 16; ++q) s += wred[q * 512 + t];
        out[(size_t)bid * D + t] = s;                    // output 0: fbar
    }
}

extern "C" void kernel_launch(void* const* d_in, const int* in_sizes, int n_in,
                              void* d_out, int out_size, void* d_ws, size_t ws_size,
                              hipStream_t stream) {
    const float* x  = (const float*)d_in[0];
    const float* W1 = (const float*)d_in[1];
    const float* b1 = (const float*)d_in[2];
    const float* w2 = (const float*)d_in[3];
    // b2 (d_in[4]) shifts all scores uniformly -> softmax-invariant -> unused.
    float* out = (float*)d_out;

    unsigned short* W1s = (unsigned short*)d_ws;   // 512 KiB pre-swizzled bf16 W1

    conv_w1<<<256, 256, 0, stream>>>(W1, W1s);
    fused<<<NGROUP, 1024, 0, stream>>>(x, W1s, b1, w2, out);
}

// Round 4
// 525.795 us; speedup vs baseline: 1.0462x; 1.0462x over previous
//
#include <hip/hip_runtime.h>
#include <hip/hip_bf16.h>

typedef short short8 __attribute__((ext_vector_type(8)));
typedef float floatx4 __attribute__((ext_vector_type(4)));

#define NGROUP 512
#define RREG 256
#define D 512
#define FBAR_ELEMS (NGROUP * D)   // 262144

__device__ __forceinline__ unsigned short f2bf(float f) {
    unsigned int u = __float_as_uint(f);
    unsigned int r = (u + 0x7fffu + ((u >> 16) & 1u)) >> 16;
    return (unsigned short)r;
}
__device__ __forceinline__ float bf2f(unsigned short h) {
    return __uint_as_float(((unsigned int)h) << 16);
}
__device__ __forceinline__ float fast_tanh(float x) {
    float cx = fminf(fmaxf(x, -9.5f), 9.5f);
    float e  = __builtin_amdgcn_exp2f(cx * 2.8853900817779268f);  // e^{2cx}
    return (e - 1.f) * __builtin_amdgcn_rcpf(e + 1.f);
}

// ---- kernel 1: W1 fp32 -> bf16, PRE-SWIZZLED chunk layout ----
// Chunk nc (64 cols x 512 k): LDS image byte L holds
// W1bf[col = nc*64 + L/1024][k elem ((L%1024) ^ ((col&7)<<4))/2].
// Stored linearly so global_load_lds (linear dest) reproduces the swizzled image.
__global__ __launch_bounds__(256) void conv_w1(const float* __restrict__ W1,
                                               unsigned short* __restrict__ W1s) {
    int tid = blockIdx.x * 256 + threadIdx.x;   // 0..65535
    int G = tid * 8;                            // byte offset in 512 KiB
    int nc = G >> 16;
    int L = G & 65535;
    int col_local = L >> 10;
    int sw = L & 1023;
    int k16 = (sw ^ ((col_local & 7) << 4)) >> 4;
    int j0 = (sw & 15) >> 1;                    // 0 or 4
    int col = nc * 64 + col_local;
    const float* src = W1 + col * 512 + k16 * 8 + j0;
    float4 v = *reinterpret_cast<const float4*>(src);
    ushort4 o;
    o.x = f2bf(v.x); o.y = f2bf(v.y); o.z = f2bf(v.z); o.w = f2bf(v.w);
    *reinterpret_cast<ushort4*>((char*)W1s + G) = o;
}

// ---- kernel 2: fully fused per-group kernel ----
// 512 blocks x 512 threads (8 waves, 32 rows/wave in two 16-row tiles).
// bf16(x) A-frags in registers (128 VGPR); inv-norm folded into epilogue +
// pooling weights; W1 double-buffered through LDS via global_load_lds.
// __launch_bounds__(512, 1): VGPR budget >= 256 under either arg-2
// interpretation (R2/R3 lesson: larger arg2 capped VGPRs at 128/64 -> spill).
__global__ __launch_bounds__(512, 1) void fused(
    const float* __restrict__ x, const unsigned short* __restrict__ W1s,
    const float* __restrict__ b1, const float* __restrict__ W2v,
    float* __restrict__ out) {

    __shared__ unsigned short B_lds[2][32768];   // 2 x 64 KiB (swizzled W1 chunk)
    __shared__ float scores_s[RREG];
    __shared__ float alpha_s[RREG];

    const int t = threadIdx.x;
    const int lane = t & 63;
    const int w = t >> 6;          // wave 0..7
    const int cl = lane & 15;
    const int hi = lane >> 4;
    const int bid = blockIdx.x;
    const size_t row0 = (size_t)bid * RREG;

    // stage one 64-col W1 chunk into LDS buffer `buf` (linear dest; src pre-swizzled)
    auto stage = [&](int buf, int nc) {
        const char* gb = (const char*)W1s + nc * 65536 + w * 8192 + lane * 16;
        char* lb = (char*)B_lds[buf] + w * 8192;
        #pragma unroll
        for (int i = 0; i < 8; ++i) {
            __builtin_amdgcn_global_load_lds(
                (const __attribute__((address_space(1))) void*)(gb + i * 1024),
                (__attribute__((address_space(3))) void*)(lb + i * 1024),
                16, 0, 0);
        }
    };

    stage(0, 0);   // in flight during the x-load phase

    // ---- load x, pack bf16 A-frags immediately, accumulate sum-of-squares ----
    // Tile m (m=0,1): lane (cl,hi) owns row w*32 + m*16 + cl; a[m][c] holds
    // k = c*32 + hi*8 + j.
    short8 a0[16], a1[16];
    float inv0, inv1;
    #pragma unroll
    for (int m = 0; m < 2; ++m) {
        const float* xp = x + (row0 + w * 32 + m * 16 + cl) * D + hi * 8;
        float ss = 0.f;
        #pragma unroll
        for (int c = 0; c < 16; ++c) {
            float4 p = *reinterpret_cast<const float4*>(xp + c * 32);
            float4 q = *reinterpret_cast<const float4*>(xp + c * 32 + 4);
            ss += p.x*p.x + p.y*p.y + p.z*p.z + p.w*p.w;
            ss += q.x*q.x + q.y*q.y + q.z*q.z + q.w*q.w;
            short8 s;
            s[0] = (short)f2bf(p.x); s[1] = (short)f2bf(p.y);
            s[2] = (short)f2bf(p.z); s[3] = (short)f2bf(p.w);
            s[4] = (short)f2bf(q.x); s[5] = (short)f2bf(q.y);
            s[6] = (short)f2bf(q.z); s[7] = (short)f2bf(q.w);
            if (m == 0) a0[c] = s; else a1[c] = s;
        }
        ss += __shfl_xor(ss, 16, 64);
        ss += __shfl_xor(ss, 32, 64);
        float inv = 1.0f / fmaxf(sqrtf(ss), 1e-12f);
        if (m == 0) inv0 = inv; else inv1 = inv;
    }

    // accumulator row r = hi*4+i of tile m needs inv of that row (lane cl=r)
    float ivr[2][4];
    #pragma unroll
    for (int i = 0; i < 4; ++i) {
        ivr[0][i] = __shfl(inv0, hi * 4 + i, 16);
        ivr[1][i] = __shfl(inv1, hi * 4 + i, 16);
    }

    __syncthreads();   // stage(0) landed (barrier drains vmcnt)

    // ---- GEMM over 8 column-chunks; epilogue folds inv, tanh, w2-dot ----
    float sp[2][4] = {{0.f,0.f,0.f,0.f},{0.f,0.f,0.f,0.f}};

    for (int nc = 0; nc < 8; ++nc) {
        if (nc < 7) stage((nc + 1) & 1, nc + 1);   // prefetch next chunk

        const char* B = (const char*)B_lds[nc & 1];
        floatx4 acc[2][4];
        #pragma unroll
        for (int j = 0; j < 4; ++j) { acc[0][j] = floatx4{0,0,0,0}; acc[1][j] = floatx4{0,0,0,0}; }

        #pragma unroll
        for (int kk = 0; kk < 16; ++kk) {
            const int kb = kk * 64 + hi * 16;
            #pragma unroll
            for (int j = 0; j < 4; ++j) {
                const int bcol = j * 16 + cl;
                short8 bf = *reinterpret_cast<const short8*>(
                    B + bcol * 1024 + (kb ^ ((bcol & 7) << 4)));
                acc[0][j] = __builtin_amdgcn_mfma_f32_16x16x32_bf16(a0[kk], bf, acc[0][j], 0, 0, 0);
                acc[1][j] = __builtin_amdgcn_mfma_f32_16x16x32_bf16(a1[kk], bf, acc[1][j], 0, 0, 0);
            }
        }

        #pragma unroll
        for (int j = 0; j < 4; ++j) {
            int col = nc * 64 + j * 16 + cl;
            float wv = W2v[col];
            float bb = b1[col];
            #pragma unroll
            for (int i = 0; i < 4; ++i) {
                sp[0][i] += wv * fast_tanh(acc[0][j][i] * ivr[0][i] + bb);
                sp[1][i] += wv * fast_tanh(acc[1][j][i] * ivr[1][i] + bb);
            }
        }
        __syncthreads();   // all waves done with buf[nc&1]; prefetch drained
    }

    // ---- reduce score partials over the 16 column-lanes; C/D row = hi*4+i ----
    #pragma unroll
    for (int m = 0; m < 2; ++m) {
        #pragma unroll
        for (int i = 0; i < 4; ++i) {
            float vv = sp[m][i];
            vv += __shfl_xor(vv, 1, 64);
            vv += __shfl_xor(vv, 2, 64);
            vv += __shfl_xor(vv, 4, 64);
            vv += __shfl_xor(vv, 8, 64);
            if (cl == 0) scores_s[w * 32 + m * 16 + hi * 4 + i] = vv;
        }
    }
    __syncthreads();

    // ---- block softmax over 256 region scores (B_lds reused as scratch) ----
    float* F = (float*)B_lds;
    float e = 0.f, scv = 0.f;
    if (t < RREG) { scv = scores_s[t]; F[t] = scv; }
    __syncthreads();
    for (int off = 128; off > 0; off >>= 1) {
        if (t < off) F[t] = fmaxf(F[t], F[t + off]);
        __syncthreads();
    }
    float mx = F[0];
    __syncthreads();
    if (t < RREG) { e = expf(scv - mx); F[t] = e; }
    __syncthreads();
    for (int off = 128; off > 0; off >>= 1) {
        if (t < off) F[t] += F[t + off];
        __syncthreads();
    }
    float denom = F[0];
    __syncthreads();
    if (t < RREG) {
        float al = e / denom;
        alpha_s[t] = al;
        out[FBAR_ELEMS + (size_t)bid * RREG + t] = al;   // output 1: alphas
    }
    __syncthreads();

    // ---- pooling: fbar[d] = sum_r (alpha_r * inv_r) * x[r][d] from A-frags ----
    float* wred = (float*)B_lds;    // [8 waves][512 d] = 16 KiB
    {
        float wt0 = alpha_s[w * 32 + cl] * inv0;
        float wt1 = alpha_s[w * 32 + 16 + cl] * inv1;
        #pragma unroll
        for (int c = 0; c < 16; ++c) {
            #pragma unroll
            for (int j = 0; j < 8; ++j) {
                float vv = wt0 * bf2f((unsigned short)a0[c][j])
                         + wt1 * bf2f((unsigned short)a1[c][j]);
                vv += __shfl_xor(vv, 1, 64);
                vv += __shfl_xor(vv, 2, 64);
                vv += __shfl_xor(vv, 4, 64);
                vv += __shfl_xor(vv, 8, 64);
                if (cl == 0) wred[w * 512 + c * 32 + hi * 8 + j] = vv;
            }
        }
    }
    __syncthreads();
    if (t < D) {
        float s = 0.f;
        #pragma unroll
        for (int q = 0; q < 8; ++q) s += wred[q * 512 + t];
        out[(size_t)bid * D + t] = s;                    // output 0: fbar
    }
}

extern "C" void kernel_launch(void* const* d_in, const int* in_sizes, int n_in,
                              void* d_out, int out_size, void* d_ws, size_t ws_size,
                              hipStream_t stream) {
    const float* x  = (const float*)d_in[0];
    const float* W1 = (const float*)d_in[1];
    const float* b1 = (const float*)d_in[2];
    const float* w2 = (const float*)d_in[3];
    // b2 (d_in[4]) shifts all scores uniformly -> softmax-invariant -> unused.
    float* out = (float*)d_out;

    unsigned short* W1s = (unsigned short*)d_ws;   // 512 KiB pre-swizzled bf16 W1

    conv_w1<<<256, 256, 0, stream>>>(W1, W1s);
    fused<<<NGROUP, 512, 0, stream>>>(x, W1s, b1, w2, out);
}

// Round 5
// 196.925 us; speedup vs baseline: 2.7933x; 2.6700x over previous
//
#include <hip/hip_runtime.h>
#include <hip/hip_bf16.h>

typedef short short8 __attribute__((ext_vector_type(8)));
typedef float floatx4 __attribute__((ext_vector_type(4)));

#define NGROUP 512
#define RREG 256
#define D 512
#define ROWS 131072
#define FBAR_ELEMS (NGROUP * D)   // 262144

__device__ __forceinline__ unsigned short f2bf(float f) {
    unsigned int u = __float_as_uint(f);
    unsigned int r = (u + 0x7fffu + ((u >> 16) & 1u)) >> 16;
    return (unsigned short)r;
}
__device__ __forceinline__ float fast_tanh(float x) {
    float cx = fminf(fmaxf(x, -9.5f), 9.5f);
    float e  = __builtin_amdgcn_exp2f(cx * 2.8853900817779268f);  // e^{2cx}
    return (e - 1.f) * __builtin_amdgcn_rcpf(e + 1.f);
}

// ---- kernel 1: W1 fp32 -> bf16, plain row-major [outcol][k] ----
__global__ __launch_bounds__(256) void conv_w1(const float* __restrict__ W1,
                                               unsigned short* __restrict__ W1bf) {
    int i = (blockIdx.x * 256 + threadIdx.x) * 4;
    float4 v = *reinterpret_cast<const float4*>(W1 + i);
    ushort4 o;
    o.x = f2bf(v.x); o.y = f2bf(v.y); o.z = f2bf(v.z); o.w = f2bf(v.w);
    *reinterpret_cast<ushort4*>(W1bf + i) = o;
}

// ---- kernel 2: score GEMM ----
// 2048 blocks x 512 threads (8 waves). Block = 64 rows of x.
// Stage bf16(x) into 64 KB swizzled LDS (ss/inv computed during staging).
// Wave w computes the full 64-row x 64-col output slice cols [w*64, w*64+64):
// A-frags from LDS (reused x4), B-frags from global (L2-resident W1bf).
// Epilogue folds inv, tanh, w2-dot; per-wave partials reduced via LDS.
__global__ __launch_bounds__(512) void score_gemm(
    const float* __restrict__ x, const unsigned short* __restrict__ W1bf,
    const float* __restrict__ b1, const float* __restrict__ W2v,
    float* __restrict__ inv_norm, float* __restrict__ scores) {

    __shared__ unsigned short A_lds[64 * 512];   // 64 KiB, swizzled
    __shared__ float inv_s[64];
    __shared__ float scorebuf[8][64];            // 2 KiB

    const int t = threadIdx.x;
    const int lane = t & 63;
    const int w = t >> 6;          // wave 0..7
    const int cl = lane & 15;
    const int hi = lane >> 4;
    const size_t row0 = (size_t)blockIdx.x * 64;

    // ---- stage A: wave w loads rows w*8 .. w*8+8 (coalesced 1 KB/instr) ----
    #pragma unroll
    for (int i = 0; i < 8; ++i) {
        int r = w * 8 + i;
        size_t g = row0 + r;
        const float* xr = x + g * (size_t)D;
        float4 v0 = *reinterpret_cast<const float4*>(xr + lane * 4);
        float4 v1 = *reinterpret_cast<const float4*>(xr + 256 + lane * 4);
        float ss = v0.x*v0.x + v0.y*v0.y + v0.z*v0.z + v0.w*v0.w
                 + v1.x*v1.x + v1.y*v1.y + v1.z*v1.z + v1.w*v1.w;
        #pragma unroll
        for (int m = 1; m < 64; m <<= 1) ss += __shfl_xor(ss, m, 64);
        float inv = 1.0f / fmaxf(sqrtf(ss), 1e-12f);
        if (lane == 0) { inv_s[r] = inv; inv_norm[g] = inv; }
        ushort4 p0, p1;
        p0.x = f2bf(v0.x); p0.y = f2bf(v0.y); p0.z = f2bf(v0.z); p0.w = f2bf(v0.w);
        p1.x = f2bf(v1.x); p1.y = f2bf(v1.y); p1.z = f2bf(v1.z); p1.w = f2bf(v1.w);
        int swz = (r & 7) << 4;
        *reinterpret_cast<ushort4*>((char*)A_lds + r * 1024 + ((lane * 8) ^ swz)) = p0;
        *reinterpret_cast<ushort4*>((char*)A_lds + r * 1024 + ((512 + lane * 8) ^ swz)) = p1;
    }
    __syncthreads();

    // ---- GEMM: acc[tile 0..3][colfrag 0..3]; K = 512 in 16 steps of 32 ----
    floatx4 acc[4][4];
    #pragma unroll
    for (int tt = 0; tt < 4; ++tt)
        #pragma unroll
        for (int f = 0; f < 4; ++f) acc[tt][f] = floatx4{0, 0, 0, 0};

    const unsigned short* Bbase = W1bf + ((size_t)(w * 64) << 9);  // cols w*64..
    const int aswz = (cl & 7) << 4;

    #pragma unroll 4
    for (int ks = 0; ks < 16; ++ks) {
        short8 bfr[4], afr[4];
        #pragma unroll
        for (int f = 0; f < 4; ++f)
            bfr[f] = *reinterpret_cast<const short8*>(
                Bbase + ((f * 16 + cl) << 9) + ks * 32 + hi * 8);
        #pragma unroll
        for (int tt = 0; tt < 4; ++tt)
            afr[tt] = *reinterpret_cast<const short8*>(
                (char*)A_lds + (tt * 16 + cl) * 1024 + ((ks * 64 + hi * 16) ^ aswz));
        #pragma unroll
        for (int tt = 0; tt < 4; ++tt)
            #pragma unroll
            for (int f = 0; f < 4; ++f)
                acc[tt][f] = __builtin_amdgcn_mfma_f32_16x16x32_bf16(
                    afr[tt], bfr[f], acc[tt][f], 0, 0, 0);
    }

    // ---- epilogue: inv, tanh, w2-dot -> per-row partials for this col-slice ----
    float sp[4][4];
    #pragma unroll
    for (int tt = 0; tt < 4; ++tt)
        #pragma unroll
        for (int i = 0; i < 4; ++i) sp[tt][i] = 0.f;

    #pragma unroll
    for (int f = 0; f < 4; ++f) {
        int col = w * 64 + f * 16 + cl;
        float wv = W2v[col];
        float bb = b1[col];
        #pragma unroll
        for (int tt = 0; tt < 4; ++tt) {
            #pragma unroll
            for (int i = 0; i < 4; ++i) {
                float iv = inv_s[tt * 16 + hi * 4 + i];
                sp[tt][i] += wv * fast_tanh(acc[tt][f][i] * iv + bb);
            }
        }
    }

    // reduce over the 16 col-lanes; C/D row = hi*4+i within tile tt
    #pragma unroll
    for (int tt = 0; tt < 4; ++tt) {
        #pragma unroll
        for (int i = 0; i < 4; ++i) {
            float v = sp[tt][i];
            v += __shfl_xor(v, 1, 64);
            v += __shfl_xor(v, 2, 64);
            v += __shfl_xor(v, 4, 64);
            v += __shfl_xor(v, 8, 64);
            if (cl == 0) scorebuf[w][tt * 16 + hi * 4 + i] = v;
        }
    }
    __syncthreads();

    // sum the 8 per-wave col-slice partials -> final scores
    if (t < 64) {
        float s = 0.f;
        #pragma unroll
        for (int q = 0; q < 8; ++q) s += scorebuf[q][t];
        scores[row0 + t] = s;
    }
}

// ---- kernel 3: softmax over r + fp32 weighted pooling ----
// 512 blocks (one per (b,n) group) x 512 threads; thread t owns d-column t.
__global__ __launch_bounds__(512) void softmax_pool(
    const float* __restrict__ x, const float* __restrict__ inv_norm,
    const float* __restrict__ scores, float* __restrict__ out) {

    __shared__ float F[RREG];
    __shared__ float wts[RREG];
    const int t = threadIdx.x;
    const int g = blockIdx.x;

    float s = 0.f, e = 0.f;
    if (t < RREG) { s = scores[g * RREG + t]; F[t] = s; }
    __syncthreads();
    for (int off = 128; off > 0; off >>= 1) {
        if (t < off) F[t] = fmaxf(F[t], F[t + off]);
        __syncthreads();
    }
    float mx = F[0];
    __syncthreads();
    if (t < RREG) { e = expf(s - mx); F[t] = e; }
    __syncthreads();
    for (int off = 128; off > 0; off >>= 1) {
        if (t < off) F[t] += F[t + off];
        __syncthreads();
    }
    float denom = F[0];
    if (t < RREG) {
        float al = e / denom;
        out[FBAR_ELEMS + (size_t)g * RREG + t] = al;          // output 1: alphas
        wts[t] = al * inv_norm[(size_t)g * RREG + t];
    }
    __syncthreads();

    // fbar[d=t] = sum_r (alpha_r * inv_r) * x[g,r,t]  (coalesced 2 KB/row)
    float a = 0.f;
    const float* xb = x + (size_t)g * RREG * D + t;
    #pragma unroll 8
    for (int r = 0; r < RREG; ++r) a += wts[r] * xb[(size_t)r * D];
    out[(size_t)g * D + t] = a;                               // output 0: fbar
}

extern "C" void kernel_launch(void* const* d_in, const int* in_sizes, int n_in,
                              void* d_out, int out_size, void* d_ws, size_t ws_size,
                              hipStream_t stream) {
    const float* x  = (const float*)d_in[0];
    const float* W1 = (const float*)d_in[1];
    const float* b1 = (const float*)d_in[2];
    const float* w2 = (const float*)d_in[3];
    // b2 (d_in[4]) shifts all scores uniformly -> softmax-invariant -> unused.
    float* out = (float*)d_out;

    unsigned short* W1bf = (unsigned short*)d_ws;                    // 512 KiB
    float* inv_norm = (float*)((char*)d_ws + 524288);                // 512 KiB
    float* scores   = (float*)((char*)d_ws + 1048576);               // 512 KiB

    conv_w1<<<256, 256, 0, stream>>>(W1, W1bf);
    score_gemm<<<ROWS / 64, 512, 0, stream>>>(x, W1bf, b1, w2, inv_norm, scores);
    softmax_pool<<<NGROUP, 512, 0, stream>>>(x, inv_norm, scores, out);
}